// Round 1
// baseline (616.101 us; speedup 1.0000x reference)
//
#include <hip/hip_runtime.h>
#include <hip/hip_bf16.h>
#include <math.h>

// ---------------------------------------------------------------------------
// SemlaSelfAttention fused kernel for MI355X (gfx950)
// B=4, N=256, D_EQUI=64, D_INV=256, D_MSG=64, N_HEADS=32, D_HEAD=8,
// D_FF=256, D_EDGE_IN=64, D_EDGE_OUT=64, D_OUT=160, IN_FEATS=256
// Outputs (flat, in order): equi_updates[4,256,3,64] | inv_updates[4,256,256]
//                           | edge_updates[4,256,256,64]
// ---------------------------------------------------------------------------

typedef __attribute__((ext_vector_type(8))) short short8;
typedef __attribute__((ext_vector_type(8))) __bf16 bf16x8;
typedef __attribute__((ext_vector_type(4))) float f32x4;

constexpr int EQUI_OFF = 0;          // 4*256*3*64   = 196608 floats
constexpr int INV_OFF  = 196608;     // 4*256*256    = 262144 floats
constexpr int EDGE_OFF = 458752;     // 4*256*256*64 = 16777216 floats

// ---- dynamic LDS layout (bytes) ----
constexpr int S_AH   = 0;        // 64x256 bf16 (swizzled) A-tile / H-tile : 32768
constexpr int S_M    = 32768;    // 256 x 97 f32 attn logits->probs       : 99328
constexpr int S_EQ   = 132096;   // 192 f32 equis[b,q,:,:]                : 768
constexpr int S_ADJ  = 132864;   // 256 int                               : 1024
constexpr int S_PMAX = 133888;   // 192 f32                               : 768
constexpr int S_PSUM = 134656;   // 192 f32                               : 768
constexpr int S_PSQ  = 135424;   // 192 f32                               : 768
constexpr int S_MC   = 136192;   // 96 f32                                : 384
constexpr int S_RS   = 136576;   // 96 f32                                : 384
constexpr int S_W    = 136960;   // 96 f32                                : 384
constexpr int S_QM   = 137344;   // 64 bf16                               : 128
constexpr int S_OI   = 137472;   // 256 f32                               : 1024
constexpr int S_OE   = 138496;   // 192 f32                               : 768
constexpr int SMEM_BYTES = 139264;

__device__ __forceinline__ unsigned short f2bf(float x) {
    unsigned u = __builtin_bit_cast(unsigned, x);
    u = u + 0x7FFFu + ((u >> 16) & 1u);   // RNE
    return (unsigned short)(u >> 16);
}
__device__ __forceinline__ unsigned pack2(float a, float b) {
    return (unsigned)f2bf(a) | ((unsigned)f2bf(b) << 16);
}

// ---------------------------------------------------------------------------
// prep kernels
// ---------------------------------------------------------------------------
__global__ void prep_weights(const float* __restrict__ mW1, const float* __restrict__ mW2,
                             short* __restrict__ W1T, short* __restrict__ W2T) {
    int idx = blockIdx.x * 256 + threadIdx.x;           // grid = 416*256 = 106496
    if (idx < 65536) {                                  // W1T[n][f] = mW1[f][n], 256x256
        int n = idx >> 8, f = idx & 255;
        W1T[idx] = (short)f2bf(mW1[f * 256 + n]);
    } else {                                            // W2T[n][f] = mW2[f][n], 160x256
        int i2 = idx - 65536;
        int n = i2 >> 8, f = i2 & 255;
        W2T[i2] = (short)f2bf(mW2[f * 160 + n]);
    }
}

__global__ void prep_proj(const float* __restrict__ invs, const float* __restrict__ equis,
                          const float* __restrict__ qW, const float* __restrict__ qb,
                          const float* __restrict__ kW, const float* __restrict__ kb,
                          const float* __restrict__ inv_inW, const float* __restrict__ inv_inb,
                          const float* __restrict__ equi_inW,
                          float* __restrict__ qm, float* __restrict__ km,
                          float* __restrict__ hf, float* __restrict__ pe) {
    int tid = threadIdx.x;
    if (blockIdx.x < 1024) {
        int r = blockIdx.x;                 // global row b*256+n
        __shared__ float sInv[256];
        sInv[tid] = invs[r * 256 + tid];
        __syncthreads();
        if (tid < 64) {
            float acc = qb[tid];
            for (int f = 0; f < 256; ++f) acc += sInv[f] * qW[f * 64 + tid];
            qm[r * 64 + tid] = acc;
        } else if (tid < 128) {
            int c = tid - 64;
            float acc = kb[c];
            for (int f = 0; f < 256; ++f) acc += sInv[f] * kW[f * 64 + c];
            km[r * 64 + c] = acc;
        }
        float acch = inv_inb[tid];
        for (int f = 0; f < 256; ++f) acch += sInv[f] * inv_inW[f * 256 + tid];
        hf[r * 256 + tid] = acch;
    } else {
        int rn = blockIdx.x - 1024;         // global row b*256+n
        if (tid < 192) {
            int d = tid >> 6, c = tid & 63;
            const float* erow = equis + (size_t)rn * 192 + d * 64;
            float acc = 0.f;
            for (int f = 0; f < 64; ++f) acc += erow[f] * equi_inW[f * 64 + c];
            pe[rn * 192 + d * 64 + c] = acc;
        }
    }
}

// ---------------------------------------------------------------------------
// main fused kernel: one block per (b,q)
// ---------------------------------------------------------------------------
__launch_bounds__(256, 1)
__global__ void semla_main(const float* __restrict__ equis, const float* __restrict__ edges,
                           const int* __restrict__ adj,
                           const float* __restrict__ mb1, const float* __restrict__ mb2,
                           const float* __restrict__ inv_outW, const float* __restrict__ inv_outb,
                           const float* __restrict__ equi_outW,
                           const short* __restrict__ W1T, const short* __restrict__ W2T,
                           const float* __restrict__ qm, const float* __restrict__ km,
                           const float* __restrict__ hf, const float* __restrict__ pe,
                           float* __restrict__ out) {
    extern __shared__ char smem[];
    float* sMf   = (float*)(smem + S_M);     // [256][97]
    float* sEQ   = (float*)(smem + S_EQ);
    int*   sAdj  = (int*)(smem + S_ADJ);
    float* sPmax = (float*)(smem + S_PMAX);
    float* sPsum = (float*)(smem + S_PSUM);
    float* sPsq  = (float*)(smem + S_PSQ);
    float* sMC   = (float*)(smem + S_MC);
    float* sRS   = (float*)(smem + S_RS);
    float* sW    = (float*)(smem + S_W);
    unsigned short* sQMb = (unsigned short*)(smem + S_QM);
    float* sOI   = (float*)(smem + S_OI);
    float* sOE   = (float*)(smem + S_OE);

    const int tid  = threadIdx.x;
    const int lane = tid & 63;
    const int w    = tid >> 6;
    const int bq   = blockIdx.x;      // b*256+q
    const int b    = bq >> 8;

    const int lrow = lane & 15;        // row (A) / col (B,D) within 16-tile
    const int kgrp = (lane >> 4) << 3; // 0,8,16,24
    const int drow = (lane >> 4) << 2; // D-frag row base

    // block-wide preloads
    if (tid < 192) sEQ[tid] = equis[(size_t)bq * 192 + tid];
    sAdj[tid] = adj[(size_t)bq * 256 + tid];
    if (tid < 64) sQMb[tid] = f2bf(qm[bq * 64 + tid]);

    // swizzled LDS tile helpers: row-major [64][256] bf16, byte ^= (row&7)<<4
    auto ldA = [&](int row, int kb) -> short8 {
        int byte = ((row << 9) + (kb << 1)) ^ ((row & 7) << 4);
        return *(const short8*)(smem + S_AH + byte);
    };
    auto stA2 = [&](int row, int col, unsigned v) {   // col even
        int byte = ((row << 9) + (col << 1)) ^ ((row & 7) << 4);
        *(unsigned*)(smem + S_AH + byte) = v;
    };
    auto stH = [&](int row, int col, unsigned short v) {
        int byte = ((row << 9) + (col << 1)) ^ ((row & 7) << 4);
        *(unsigned short*)(smem + S_AH + byte) = v;
    };

    for (int jc = 0; jc < 4; ++jc) {
        __syncthreads();   // also covers initial preloads / prev-chunk GEMM2 reads

        // ---- build A tile: feats[j_loc][0:256] in bf16 ----
        if (w == 0) {                       // cols 0..63 : qm (row-invariant)
            unsigned short qv = sQMb[lane];
            #pragma unroll
            for (int r = 0; r < 64; ++r) {
                int byte = (((r << 9) + (lane << 1))) ^ ((r & 7) << 4);
                *(unsigned short*)(smem + S_AH + byte) = qv;
            }
        } else if (w == 1) {                // cols 64..127 : km[b, j]
            int r = lane;
            const float* src = km + (size_t)((b << 8) + (jc << 6) + r) * 64;
            #pragma unroll
            for (int it = 0; it < 16; ++it) {
                f32x4 v = *(const f32x4*)(src + it * 4);
                int col = 64 + it * 4;
                stA2(r, col,     pack2(v.x, v.y));
                stA2(r, col + 2, pack2(v.z, v.w));
            }
        } else if (w == 2) {                // cols 128..191 : dot(q, j)
            int r = lane;
            const float* erow = equis + (size_t)((b << 8) + (jc << 6) + r) * 192;
            #pragma unroll
            for (int c4 = 0; c4 < 16; ++c4) {
                f32x4 a = (f32x4)(0.f);
                #pragma unroll
                for (int d = 0; d < 3; ++d) {
                    f32x4 e = *(const f32x4*)(erow + d * 64 + c4 * 4);
                    f32x4 qv = *(const f32x4*)(sEQ + d * 64 + c4 * 4);
                    a += e * qv;
                }
                int col = 128 + c4 * 4;
                stA2(r, col,     pack2(a.x, a.y));
                stA2(r, col + 2, pack2(a.z, a.w));
            }
        } else {                            // cols 192..255 : edges[b,q,j]
            const float* ebase = edges + ((size_t)bq * 256 + (jc << 6)) * 64;
            #pragma unroll
            for (int it = 0; it < 16; ++it) {
                int vi = it * 64 + lane;
                f32x4 v = ((const f32x4*)ebase)[vi];
                int r = vi >> 4, c4 = vi & 15;
                int col = 192 + c4 * 4;
                stA2(r, col,     pack2(v.x, v.y));
                stA2(r, col + 2, pack2(v.z, v.w));
            }
        }
        __syncthreads();

        // ---- GEMM1: H = silu(A @ W1 + b1), wave w owns cols [64w, 64w+64) ----
        f32x4 acc[4][4];
        #pragma unroll
        for (int mi = 0; mi < 4; ++mi)
            #pragma unroll
            for (int ni = 0; ni < 4; ++ni) acc[mi][ni] = (f32x4)(0.f);

        #pragma unroll
        for (int k0 = 0; k0 < 256; k0 += 32) {
            int kb = k0 + kgrp;
            short8 a0 = ldA(lrow, kb), a1 = ldA(16 + lrow, kb),
                   a2 = ldA(32 + lrow, kb), a3 = ldA(48 + lrow, kb);
            short8 bf[4];
            #pragma unroll
            for (int ni = 0; ni < 4; ++ni) {
                int n = (w << 6) + (ni << 4) + lrow;
                bf[ni] = *(const short8*)(W1T + n * 256 + kb);
            }
            #pragma unroll
            for (int ni = 0; ni < 4; ++ni) {
                bf16x8 bb = __builtin_bit_cast(bf16x8, bf[ni]);
                acc[0][ni] = __builtin_amdgcn_mfma_f32_16x16x32_bf16(__builtin_bit_cast(bf16x8, a0), bb, acc[0][ni], 0, 0, 0);
                acc[1][ni] = __builtin_amdgcn_mfma_f32_16x16x32_bf16(__builtin_bit_cast(bf16x8, a1), bb, acc[1][ni], 0, 0, 0);
                acc[2][ni] = __builtin_amdgcn_mfma_f32_16x16x32_bf16(__builtin_bit_cast(bf16x8, a2), bb, acc[2][ni], 0, 0, 0);
                acc[3][ni] = __builtin_amdgcn_mfma_f32_16x16x32_bf16(__builtin_bit_cast(bf16x8, a3), bb, acc[3][ni], 0, 0, 0);
            }
        }
        __syncthreads();   // everyone done reading A before overwriting with H

        #pragma unroll
        for (int mi = 0; mi < 4; ++mi)
            #pragma unroll
            for (int ni = 0; ni < 4; ++ni) {
                int n = (w << 6) + (ni << 4) + lrow;
                float bias = mb1[n];
                #pragma unroll
                for (int r = 0; r < 4; ++r) {
                    float x = acc[mi][ni][r] + bias;
                    float h = x / (1.f + __expf(-x));   // silu
                    stH((mi << 4) + drow + r, n, f2bf(h));
                }
            }
        __syncthreads();

        // ---- GEMM2: msgs = H @ W2 + b2 ; tiles 3/3/2/2 across waves ----
        const int ntiles = (w < 2) ? 3 : 2;
        const int nbase  = (w < 2) ? w * 48 : 96 + (w - 2) * 32;
        f32x4 acc2[4][3];
        #pragma unroll
        for (int mi = 0; mi < 4; ++mi)
            #pragma unroll
            for (int ti = 0; ti < 3; ++ti) acc2[mi][ti] = (f32x4)(0.f);

        #pragma unroll
        for (int k0 = 0; k0 < 256; k0 += 32) {
            int kb = k0 + kgrp;
            short8 a0 = ldA(lrow, kb), a1 = ldA(16 + lrow, kb),
                   a2 = ldA(32 + lrow, kb), a3 = ldA(48 + lrow, kb);
            short8 bt[3];
            #pragma unroll
            for (int ti = 0; ti < 3; ++ti)
                if (ti < ntiles) {
                    int n = nbase + (ti << 4) + lrow;
                    bt[ti] = *(const short8*)(W2T + n * 256 + kb);
                }
            #pragma unroll
            for (int ti = 0; ti < 3; ++ti)
                if (ti < ntiles) {
                    bf16x8 bb = __builtin_bit_cast(bf16x8, bt[ti]);
                    acc2[0][ti] = __builtin_amdgcn_mfma_f32_16x16x32_bf16(__builtin_bit_cast(bf16x8, a0), bb, acc2[0][ti], 0, 0, 0);
                    acc2[1][ti] = __builtin_amdgcn_mfma_f32_16x16x32_bf16(__builtin_bit_cast(bf16x8, a1), bb, acc2[1][ti], 0, 0, 0);
                    acc2[2][ti] = __builtin_amdgcn_mfma_f32_16x16x32_bf16(__builtin_bit_cast(bf16x8, a2), bb, acc2[2][ti], 0, 0, 0);
                    acc2[3][ti] = __builtin_amdgcn_mfma_f32_16x16x32_bf16(__builtin_bit_cast(bf16x8, a3), bb, acc2[3][ti], 0, 0, 0);
                }
        }

        // epilogue: edge cols -> global, attn cols -> sMf
        #pragma unroll
        for (int mi = 0; mi < 4; ++mi)
            #pragma unroll
            for (int ti = 0; ti < 3; ++ti)
                if (ti < ntiles) {
                    int n = nbase + (ti << 4) + lrow;
                    float bias = mb2[n];
                    #pragma unroll
                    for (int r = 0; r < 4; ++r) {
                        int jl = (mi << 4) + drow + r;
                        int j  = (jc << 6) + jl;
                        float v = acc2[mi][ti][r] + bias;
                        if (n >= 96)
                            out[EDGE_OFF + ((size_t)bq * 256 + j) * 64 + (n - 96)] = v;
                        else
                            sMf[j * 97 + n] = v;
                    }
                }
    }
    __syncthreads();

    // ---- softmax over k for 96 attn columns (2 threads per column) ----
    if (tid < 192) {
        int c = tid >> 1, half = tid & 1;
        float lmax = -3.4e38f;
        for (int j = half * 128; j < half * 128 + 128; ++j)
            if (sAdj[j]) lmax = fmaxf(lmax, sMf[j * 97 + c]);
        sPmax[tid] = lmax;
    }
    __syncthreads();
    if (tid < 192) {
        int c = tid >> 1, half = tid & 1;
        float m = fmaxf(sPmax[2 * c], sPmax[2 * c + 1]);
        float ls = 0.f, lq = 0.f;
        for (int j = half * 128; j < half * 128 + 128; ++j)
            if (sAdj[j]) {
                float e = __expf(sMf[j * 97 + c] - m);
                ls += e; lq += e * e;
            }
        sPsum[tid] = ls; sPsq[tid] = lq;
    }
    __syncthreads();
    if (tid < 96) {
        int c = tid;
        float m = fmaxf(sPmax[2 * c], sPmax[2 * c + 1]);
        float s = sPsum[2 * c] + sPsum[2 * c + 1];
        float qq = sPsq[2 * c] + sPsq[2 * c + 1];
        float rs = (s > 0.f) ? 1.f / s : 0.f;
        sMC[c] = m; sRS[c] = rs; sW[c] = sqrtf(qq) * rs;
    }
    __syncthreads();
    // normalize in place: sMf <- p
    for (int idx = tid; idx < 24576; idx += 256) {
        int j = idx / 96;
        int c = idx - j * 96;
        float v = sAdj[j] ? __expf(sMf[j * 97 + c] - sMC[c]) * sRS[c] : 0.f;
        sMf[j * 97 + c] = v;
    }
    __syncthreads();

    // ---- attention einsums ----
    {   // out_i[h][d] = w_i[h] * sum_j p[j,h] * hf[b,j,h*8+d]; thread = h*8+d
        int h = tid >> 3;
        const float* hfp = hf + ((size_t)b << 16) + tid;
        float acc = 0.f;
        #pragma unroll 4
        for (int j = 0; j < 256; ++j)
            acc = fmaf(sMf[j * 97 + h], hfp[j << 8], acc);
        sOI[tid] = acc * sW[h];
    }
    if (tid < 192) {  // out_e[d][c] = w_e[c] * sum_j p[j,32+c] * pe[b,j,d,c]
        int d = tid >> 6, c = tid & 63;
        const float* pep = pe + (size_t)b * 49152 + d * 64 + c;
        float acc = 0.f;
        #pragma unroll 4
        for (int j = 0; j < 256; ++j)
            acc = fmaf(sMf[j * 97 + 32 + c], pep[j * 192], acc);
        sOE[d * 64 + c] = acc * sW[32 + c];
    }
    __syncthreads();

    // ---- final projections ----
    {   // inv_updates[b,q,n] = sOI(256) @ inv_outW + inv_outb
        float acc = inv_outb[tid];
        #pragma unroll 4
        for (int f = 0; f < 256; ++f)
            acc = fmaf(sOI[f], inv_outW[f * 256 + tid], acc);
        out[INV_OFF + (size_t)bq * 256 + tid] = acc;
    }
    if (tid < 192) {  // equi_updates[b,q,d,c] = sOE[d,:] @ equi_outW
        int d = tid >> 6, c = tid & 63;
        float acc = 0.f;
        #pragma unroll
        for (int f = 0; f < 64; ++f)
            acc = fmaf(sOE[d * 64 + f], equi_outW[f * 64 + c], acc);
        out[(size_t)bq * 192 + tid] = acc;
    }
}

// ---------------------------------------------------------------------------
extern "C" void kernel_launch(void* const* d_in, const int* in_sizes, int n_in,
                              void* d_out, int out_size, void* d_ws, size_t ws_size,
                              hipStream_t stream) {
    const float* equis    = (const float*)d_in[0];
    const float* invs     = (const float*)d_in[1];
    const float* edges    = (const float*)d_in[2];
    const int*   adj      = (const int*)d_in[3];
    const float* qW       = (const float*)d_in[4];
    const float* qb       = (const float*)d_in[5];
    const float* kW       = (const float*)d_in[6];
    const float* kb       = (const float*)d_in[7];
    const float* mW1      = (const float*)d_in[8];
    const float* mb1      = (const float*)d_in[9];
    const float* mW2      = (const float*)d_in[10];
    const float* mb2      = (const float*)d_in[11];
    const float* inv_inW  = (const float*)d_in[12];
    const float* inv_inb  = (const float*)d_in[13];
    const float* inv_outW = (const float*)d_in[14];
    const float* inv_outb = (const float*)d_in[15];
    const float* equi_inW = (const float*)d_in[16];
    const float* equi_outW= (const float*)d_in[17];

    char* ws = (char*)d_ws;
    short* W1T = (short*)(ws + 0);        // 131072 B
    short* W2T = (short*)(ws + 131072);   // 81920 B
    float* qm  = (float*)(ws + 212992);   // 262144 B
    float* km  = (float*)(ws + 475136);   // 262144 B
    float* hf  = (float*)(ws + 737280);   // 1048576 B
    float* pe  = (float*)(ws + 1785856);  // 786432 B  (total 2572288 B)

    hipFuncSetAttribute((const void*)semla_main,
                        hipFuncAttributeMaxDynamicSharedMemorySize, SMEM_BYTES);

    prep_weights<<<416, 256, 0, stream>>>(mW1, mW2, W1T, W2T);
    prep_proj<<<2048, 256, 0, stream>>>(invs, equis, qW, qb, kW, kb,
                                        inv_inW, inv_inb, equi_inW, qm, km, hf, pe);
    semla_main<<<1024, 256, SMEM_BYTES, stream>>>(equis, edges, adj, mb1, mb2,
                                                  inv_outW, inv_outb, equi_outW,
                                                  W1T, W2T, qm, km, hf, pe,
                                                  (float*)d_out);
}

// Round 2
// 276.115 us; speedup vs baseline: 2.2313x; 2.2313x over previous
//
#include <hip/hip_runtime.h>
#include <hip/hip_bf16.h>
#include <math.h>

// ---------------------------------------------------------------------------
// SemlaSelfAttention — split design for MI355X (gfx950)
//   prep_weights : bf16-transpose W1 (K=128 tail) and W2
//   prep_proj    : qm, km, hf, pe projections
//   prep_c12     : c1[b,q][f] = mb1 + qm·W1[0:64,:]   (rank-folded qm cols)
//                  c2[b,j][f] =       km·W1[64:128,:] (rank-folded km cols)
//   semla_gemm   : per (b,q,jchunk): feats(dot|edges) -> GEMM1(K=128) -> silu
//                  -> GEMM2 -> edge cols to out, attn cols (bf16) to ws
//   semla_attn   : per (b,q): softmax over k + einsums + output projections
// ---------------------------------------------------------------------------

typedef __attribute__((ext_vector_type(8))) short short8;
typedef __attribute__((ext_vector_type(8))) __bf16 bf16x8;
typedef __attribute__((ext_vector_type(4))) float f32x4;

constexpr int EQUI_OFF = 0;          // 4*256*3*64   floats
constexpr int INV_OFF  = 196608;     // 4*256*256
constexpr int EDGE_OFF = 458752;     // 4*256*256*64

__device__ __forceinline__ unsigned short f2bf(float x) {
    unsigned u = __builtin_bit_cast(unsigned, x);
    u = u + 0x7FFFu + ((u >> 16) & 1u);   // RNE
    return (unsigned short)(u >> 16);
}
__device__ __forceinline__ unsigned pack2(float a, float b) {
    return (unsigned)f2bf(a) | ((unsigned)f2bf(b) << 16);
}
__device__ __forceinline__ float bf2f(unsigned short u) {
    return __builtin_bit_cast(float, ((unsigned)u) << 16);
}

// ---------------------------------------------------------------------------
// prep kernels
// ---------------------------------------------------------------------------
__global__ void prep_weights(const float* __restrict__ mW1, const float* __restrict__ mW2,
                             short* __restrict__ W1T, short* __restrict__ W2T) {
    int idx = blockIdx.x * 256 + threadIdx.x;           // grid = 288*256 = 73728
    if (idx < 32768) {                                  // W1T[n][kk] = mW1[128+kk][n]
        int n = idx >> 7, kk = idx & 127;
        W1T[idx] = (short)f2bf(mW1[(128 + kk) * 256 + n]);
    } else {                                            // W2T[n][f] = mW2[f][n], 160x256
        int i2 = idx - 32768;
        int n = i2 >> 8, f = i2 & 255;
        W2T[i2] = (short)f2bf(mW2[f * 160 + n]);
    }
}

__global__ void prep_proj(const float* __restrict__ invs, const float* __restrict__ equis,
                          const float* __restrict__ qW, const float* __restrict__ qb,
                          const float* __restrict__ kW, const float* __restrict__ kb,
                          const float* __restrict__ inv_inW, const float* __restrict__ inv_inb,
                          const float* __restrict__ equi_inW,
                          float* __restrict__ qm, float* __restrict__ km,
                          float* __restrict__ hf, float* __restrict__ pe) {
    int tid = threadIdx.x;
    if (blockIdx.x < 1024) {
        int r = blockIdx.x;                 // global row b*256+n
        __shared__ float sInv[256];
        sInv[tid] = invs[r * 256 + tid];
        __syncthreads();
        if (tid < 64) {
            float acc = qb[tid];
            for (int f = 0; f < 256; ++f) acc += sInv[f] * qW[f * 64 + tid];
            qm[r * 64 + tid] = acc;
        } else if (tid < 128) {
            int c = tid - 64;
            float acc = kb[c];
            for (int f = 0; f < 256; ++f) acc += sInv[f] * kW[f * 64 + c];
            km[r * 64 + c] = acc;
        }
        float acch = inv_inb[tid];
        for (int f = 0; f < 256; ++f) acch += sInv[f] * inv_inW[f * 256 + tid];
        hf[r * 256 + tid] = acch;
    } else {
        int rn = blockIdx.x - 1024;
        if (tid < 192) {
            int d = tid >> 6, c = tid & 63;
            const float* erow = equis + (size_t)rn * 192 + d * 64;
            float acc = 0.f;
            for (int f = 0; f < 64; ++f) acc += erow[f] * equi_inW[f * 64 + c];
            pe[rn * 192 + d * 64 + c] = acc;
        }
    }
}

__global__ void prep_c12(const float* __restrict__ qm, const float* __restrict__ km,
                         const float* __restrict__ mW1, const float* __restrict__ mb1,
                         float* __restrict__ c1, float* __restrict__ c2) {
    int tid = threadIdx.x;
    __shared__ float s[64];
    if (blockIdx.x < 1024) {
        int r = blockIdx.x;                 // b*256+q
        if (tid < 64) s[tid] = qm[r * 64 + tid];
        __syncthreads();
        float acc = mb1[tid];
        #pragma unroll 8
        for (int k = 0; k < 64; ++k) acc = fmaf(s[k], mW1[k * 256 + tid], acc);
        c1[r * 256 + tid] = acc;
    } else {
        int r = blockIdx.x - 1024;          // b*256+j
        if (tid < 64) s[tid] = km[r * 64 + tid];
        __syncthreads();
        float acc = 0.f;
        #pragma unroll 8
        for (int k = 0; k < 64; ++k) acc = fmaf(s[k], mW1[(64 + k) * 256 + tid], acc);
        c2[r * 256 + tid] = acc;
    }
}

// ---------------------------------------------------------------------------
// GEMM kernel: one block per (b,q,jc); 4 waves; ~33.5 KB LDS -> 4 blocks/CU
// ---------------------------------------------------------------------------
constexpr int GA_AH = 0;        // A: 64x128 bf16 (16 KB) then H: 64x256 bf16 (32 KB)
constexpr int GA_EQ = 32768;    // 192 f32
constexpr int GA_BYTES = 33536;

__launch_bounds__(256, 4)
__global__ void semla_gemm(const float* __restrict__ equis, const float* __restrict__ edges,
                           const float* __restrict__ mb2,
                           const short* __restrict__ W1T, const short* __restrict__ W2T,
                           const float* __restrict__ c1, const float* __restrict__ c2,
                           float* __restrict__ out, unsigned short* __restrict__ logits) {
    extern __shared__ char smem[];
    float* sEQ = (float*)(smem + GA_EQ);

    const int tid  = threadIdx.x;
    const int lane = tid & 63;
    const int w    = tid >> 6;
    const int bid  = blockIdx.x;        // bq*4 + jc
    const int bq   = bid >> 2;
    const int jc   = bid & 3;
    const int b    = bq >> 8;

    const int lrow = lane & 15;
    const int kgrp = (lane >> 4) << 3;
    const int drow = (lane >> 4) << 2;

    if (tid < 192) sEQ[tid] = equis[(size_t)bq * 192 + tid];

    // hoisted per-thread constants
    float c1v[4];
    #pragma unroll
    for (int ni = 0; ni < 4; ++ni)
        c1v[ni] = c1[bq * 256 + (w << 6) + (ni << 4) + lrow];
    const int ntiles = (w < 2) ? 3 : 2;
    const int nbase  = (w < 2) ? w * 48 : 96 + (w - 2) * 32;
    float b2v[3];
    #pragma unroll
    for (int ti = 0; ti < 3; ++ti)
        if (ti < ntiles) b2v[ti] = mb2[nbase + (ti << 4) + lrow];

    // LDS helpers
    auto stA2 = [&](int row, int col, unsigned v) {     // A tile: [64][128] bf16
        int byte = ((row << 8) + (col << 1)) ^ ((row & 7) << 4);
        *(unsigned*)(smem + GA_AH + byte) = v;
    };
    auto ldA = [&](int row, int kb) -> short8 {
        int byte = ((row << 8) + (kb << 1)) ^ ((row & 7) << 4);
        return *(const short8*)(smem + GA_AH + byte);
    };
    auto stH = [&](int row, int col, unsigned short v) { // H tile: [64][256] bf16
        int byte = ((row << 9) + (col << 1)) ^ ((row & 7) << 4);
        *(unsigned short*)(smem + GA_AH + byte) = v;
    };
    auto ldH = [&](int row, int kb) -> short8 {
        int byte = ((row << 9) + (kb << 1)) ^ ((row & 7) << 4);
        return *(const short8*)(smem + GA_AH + byte);
    };

    __syncthreads();   // sEQ visible

    // ---- build A tile: cols 0..63 = dot(q, j), cols 64..127 = edges[b,q,j] ----
    {
        int r = tid >> 2, qq = tid & 3;
        const float* erow = equis + (size_t)((b << 8) + (jc << 6) + r) * 192;
        #pragma unroll
        for (int i = 0; i < 4; ++i) {
            int c4 = (i << 2) + qq;
            f32x4 a = (f32x4)(0.f);
            #pragma unroll
            for (int d = 0; d < 3; ++d) {
                f32x4 e  = *(const f32x4*)(erow + d * 64 + c4 * 4);
                f32x4 qv = *(const f32x4*)(sEQ + d * 64 + c4 * 4);
                a += e * qv;
            }
            stA2(r, c4 * 4,     pack2(a.x, a.y));
            stA2(r, c4 * 4 + 2, pack2(a.z, a.w));
        }
        const float* ebase = edges + ((size_t)bq * 256 + (jc << 6)) * 64;
        #pragma unroll
        for (int it = 0; it < 4; ++it) {
            int vi = it * 256 + tid;
            f32x4 v = ((const f32x4*)ebase)[vi];
            int rr = vi >> 4, c4 = vi & 15;
            stA2(rr, 64 + c4 * 4,     pack2(v.x, v.y));
            stA2(rr, 64 + c4 * 4 + 2, pack2(v.z, v.w));
        }
    }
    __syncthreads();

    // ---- GEMM1: H = silu(A @ W1[128:256] + c1 + c2), K = 128 ----
    f32x4 acc[4][4];
    #pragma unroll
    for (int mi = 0; mi < 4; ++mi)
        #pragma unroll
        for (int ni = 0; ni < 4; ++ni) acc[mi][ni] = (f32x4)(0.f);

    #pragma unroll
    for (int k0 = 0; k0 < 128; k0 += 32) {
        int kb = k0 + kgrp;
        short8 a0 = ldA(lrow, kb), a1 = ldA(16 + lrow, kb),
               a2 = ldA(32 + lrow, kb), a3 = ldA(48 + lrow, kb);
        short8 bf[4];
        #pragma unroll
        for (int ni = 0; ni < 4; ++ni) {
            int n = (w << 6) + (ni << 4) + lrow;
            bf[ni] = *(const short8*)(W1T + n * 128 + kb);
        }
        #pragma unroll
        for (int ni = 0; ni < 4; ++ni) {
            bf16x8 bb = __builtin_bit_cast(bf16x8, bf[ni]);
            acc[0][ni] = __builtin_amdgcn_mfma_f32_16x16x32_bf16(__builtin_bit_cast(bf16x8, a0), bb, acc[0][ni], 0, 0, 0);
            acc[1][ni] = __builtin_amdgcn_mfma_f32_16x16x32_bf16(__builtin_bit_cast(bf16x8, a1), bb, acc[1][ni], 0, 0, 0);
            acc[2][ni] = __builtin_amdgcn_mfma_f32_16x16x32_bf16(__builtin_bit_cast(bf16x8, a2), bb, acc[2][ni], 0, 0, 0);
            acc[3][ni] = __builtin_amdgcn_mfma_f32_16x16x32_bf16(__builtin_bit_cast(bf16x8, a3), bb, acc[3][ni], 0, 0, 0);
        }
    }
    __syncthreads();   // all waves done reading A

    // epilogue: add folded biases, silu, store H (bf16) to LDS
    const float* c2base = c2 + ((size_t)((b << 8) + (jc << 6)) << 8);
    #pragma unroll
    for (int mi = 0; mi < 4; ++mi)
        #pragma unroll
        for (int r = 0; r < 4; ++r) {
            int row = (mi << 4) + drow + r;
            const float* c2row = c2base + (row << 8);
            #pragma unroll
            for (int ni = 0; ni < 4; ++ni) {
                int n = (w << 6) + (ni << 4) + lrow;
                float x = acc[mi][ni][r] + c1v[ni] + c2row[n];
                float h = x / (1.f + __expf(-x));   // silu
                stH(row, n, f2bf(h));
            }
        }
    __syncthreads();

    // ---- GEMM2: msgs = H @ W2 + b2 ; n-tiles 3/3/2/2 across waves ----
    f32x4 acc2[4][3];
    #pragma unroll
    for (int mi = 0; mi < 4; ++mi)
        #pragma unroll
        for (int ti = 0; ti < 3; ++ti) acc2[mi][ti] = (f32x4)(0.f);

    #pragma unroll
    for (int k0 = 0; k0 < 256; k0 += 32) {
        int kb = k0 + kgrp;
        short8 a0 = ldH(lrow, kb), a1 = ldH(16 + lrow, kb),
               a2 = ldH(32 + lrow, kb), a3 = ldH(48 + lrow, kb);
        short8 bt[3];
        #pragma unroll
        for (int ti = 0; ti < 3; ++ti)
            if (ti < ntiles) bt[ti] = *(const short8*)(W2T + (nbase + (ti << 4) + lrow) * 256 + kb);
        #pragma unroll
        for (int ti = 0; ti < 3; ++ti)
            if (ti < ntiles) {
                bf16x8 bb = __builtin_bit_cast(bf16x8, bt[ti]);
                acc2[0][ti] = __builtin_amdgcn_mfma_f32_16x16x32_bf16(__builtin_bit_cast(bf16x8, a0), bb, acc2[0][ti], 0, 0, 0);
                acc2[1][ti] = __builtin_amdgcn_mfma_f32_16x16x32_bf16(__builtin_bit_cast(bf16x8, a1), bb, acc2[1][ti], 0, 0, 0);
                acc2[2][ti] = __builtin_amdgcn_mfma_f32_16x16x32_bf16(__builtin_bit_cast(bf16x8, a2), bb, acc2[2][ti], 0, 0, 0);
                acc2[3][ti] = __builtin_amdgcn_mfma_f32_16x16x32_bf16(__builtin_bit_cast(bf16x8, a3), bb, acc2[3][ti], 0, 0, 0);
            }
    }

    // epilogue: edge cols -> out (f32), attn cols -> logits ws (bf16)
    #pragma unroll
    for (int mi = 0; mi < 4; ++mi)
        #pragma unroll
        for (int ti = 0; ti < 3; ++ti)
            if (ti < ntiles) {
                int n = nbase + (ti << 4) + lrow;
                #pragma unroll
                for (int r = 0; r < 4; ++r) {
                    int j = (jc << 6) + (mi << 4) + drow + r;
                    float v = acc2[mi][ti][r] + b2v[ti];
                    if (n >= 96)
                        out[EDGE_OFF + ((size_t)bq * 256 + j) * 64 + (n - 96)] = v;
                    else
                        logits[((size_t)bq * 256 + j) * 96 + n] = f2bf(v);
                }
            }
}

// ---------------------------------------------------------------------------
// attention kernel: one block per (b,q); ~53 KB LDS -> 3 blocks/CU
// ---------------------------------------------------------------------------
constexpr int BA_SP   = 0;        // 96 x (2x132) bf16 = 50688
constexpr int BA_MASK = 50688;    // 256 f32
constexpr int BA_WC   = 51712;    // 96 f32
constexpr int BA_OI   = 52096;    // 256 f32
constexpr int BA_OE   = 53120;    // 192 f32
constexpr int BA_BYTES = 53888;

__launch_bounds__(256, 3)
__global__ void semla_attn(const int* __restrict__ adj, const unsigned short* __restrict__ logits,
                           const float* __restrict__ hf, const float* __restrict__ pe,
                           const float* __restrict__ inv_outW, const float* __restrict__ inv_outb,
                           const float* __restrict__ equi_outW,
                           float* __restrict__ out) {
    extern __shared__ char smem[];
    unsigned short* sP = (unsigned short*)(smem + BA_SP);   // row c: [2][132], 128 used per half
    float* sMask = (float*)(smem + BA_MASK);
    float* sWc   = (float*)(smem + BA_WC);
    float* sOI   = (float*)(smem + BA_OI);
    float* sOE   = (float*)(smem + BA_OE);

    const int tid = threadIdx.x;
    const int bq  = blockIdx.x;
    const int b   = bq >> 8;

    sMask[tid] = adj[(size_t)bq * 256 + tid] ? 0.f : -1e30f;

    // load logits row j=tid (96 bf16) and transpose into sP[c][...]
    {
        const unsigned short* lrow = logits + ((size_t)bq * 256 + tid) * 96;
        short8 v[12];
        #pragma unroll
        for (int t = 0; t < 12; ++t) v[t] = ((const short8*)lrow)[t];
        int half = tid >> 7, jq = tid & 127;
        #pragma unroll
        for (int t = 0; t < 12; ++t)
            #pragma unroll
            for (int e = 0; e < 8; ++e)
                sP[(t * 8 + e) * 264 + half * 132 + jq] = (unsigned short)v[t][e];
    }
    __syncthreads();

    // ---- softmax over j for 96 columns; 2 lanes per column ----
    if (tid < 192) {
        int c = tid >> 1, h = tid & 1;
        unsigned short* base = sP + c * 264 + h * 132;
        const float* mbase = sMask + h * 128;
        float lm = -1e30f;
        #pragma unroll 4
        for (int t = 0; t < 16; ++t) {
            short8 x = *(const short8*)(base + t * 8);
            #pragma unroll
            for (int e = 0; e < 8; ++e)
                lm = fmaxf(lm, bf2f((unsigned short)x[e]) + mbase[t * 8 + e]);
        }
        float m = fmaxf(lm, __shfl_xor(lm, 1));
        float ls = 0.f, lq = 0.f;
        #pragma unroll 4
        for (int t = 0; t < 16; ++t) {
            short8 x = *(const short8*)(base + t * 8);
            #pragma unroll
            for (int e = 0; e < 8; ++e) {
                float ev = __expf(bf2f((unsigned short)x[e]) + mbase[t * 8 + e] - m);
                ls += ev; lq += ev * ev;
            }
        }
        ls += __shfl_xor(ls, 1);
        lq += __shfl_xor(lq, 1);
        float rs = (ls > 0.f) ? 1.f / ls : 0.f;
        if (h == 0) sWc[c] = sqrtf(lq) * rs;
        #pragma unroll 2
        for (int t = 0; t < 16; ++t) {
            short8 x = *(const short8*)(base + t * 8);
            short8 o;
            #pragma unroll
            for (int e = 0; e < 8; ++e) {
                float p = __expf(bf2f((unsigned short)x[e]) + mbase[t * 8 + e] - m) * rs;
                o[e] = (short)f2bf(p);
            }
            *(short8*)(base + t * 8) = o;
        }
    }
    __syncthreads();

    // ---- einsums ----
    {   // out_i: thread = h*8+d
        int h = tid >> 3;
        const unsigned short* prow = sP + h * 264;
        const float* hfp = hf + ((size_t)b << 16) + tid;
        float acc = 0.f;
        #pragma unroll 4
        for (int j = 0; j < 128; ++j)
            acc = fmaf(bf2f(prow[j]), hfp[j << 8], acc);
        #pragma unroll 4
        for (int j = 128; j < 256; ++j)
            acc = fmaf(bf2f(prow[j + 4]), hfp[j << 8], acc);
        sOI[tid] = acc * sWc[h];
    }
    if (tid < 192) {  // out_e: (d, c)
        int d = tid >> 6, c = tid & 63;
        const unsigned short* prow = sP + (32 + c) * 264;
        const float* pep = pe + (size_t)b * 49152 + d * 64 + c;
        float acc = 0.f;
        #pragma unroll 4
        for (int j = 0; j < 128; ++j)
            acc = fmaf(bf2f(prow[j]), pep[j * 192], acc);
        #pragma unroll 4
        for (int j = 128; j < 256; ++j)
            acc = fmaf(bf2f(prow[j + 4]), pep[j * 192], acc);
        sOE[tid] = acc * sWc[32 + c];
    }
    __syncthreads();

    // ---- final projections ----
    {
        float acc = inv_outb[tid];
        #pragma unroll 4
        for (int f = 0; f < 256; ++f)
            acc = fmaf(sOI[f], inv_outW[f * 256 + tid], acc);
        out[INV_OFF + (size_t)bq * 256 + tid] = acc;
    }
    if (tid < 192) {
        int d = tid >> 6, c = tid & 63;
        float acc = 0.f;
        #pragma unroll
        for (int f = 0; f < 64; ++f)
            acc = fmaf(sOE[d * 64 + f], equi_outW[f * 64 + c], acc);
        out[(size_t)bq * 192 + tid] = acc;
    }
}

// ---------------------------------------------------------------------------
extern "C" void kernel_launch(void* const* d_in, const int* in_sizes, int n_in,
                              void* d_out, int out_size, void* d_ws, size_t ws_size,
                              hipStream_t stream) {
    const float* equis    = (const float*)d_in[0];
    const float* invs     = (const float*)d_in[1];
    const float* edges    = (const float*)d_in[2];
    const int*   adj      = (const int*)d_in[3];
    const float* qW       = (const float*)d_in[4];
    const float* qb       = (const float*)d_in[5];
    const float* kW       = (const float*)d_in[6];
    const float* kb       = (const float*)d_in[7];
    const float* mW1      = (const float*)d_in[8];
    const float* mb1      = (const float*)d_in[9];
    const float* mW2      = (const float*)d_in[10];
    const float* mb2      = (const float*)d_in[11];
    const float* inv_inW  = (const float*)d_in[12];
    const float* inv_inb  = (const float*)d_in[13];
    const float* inv_outW = (const float*)d_in[14];
    const float* inv_outb = (const float*)d_in[15];
    const float* equi_inW = (const float*)d_in[16];
    const float* equi_outW= (const float*)d_in[17];

    char* ws = (char*)d_ws;
    short* W1T = (short*)(ws + 0);            //  65536 B (256x128 bf16)
    short* W2T = (short*)(ws + 65536);        //  81920 B (160x256 bf16)
    float* qm  = (float*)(ws + 147456);       // 262144 B
    float* km  = (float*)(ws + 409600);       // 262144 B
    float* hf  = (float*)(ws + 671744);       // 1 MiB
    float* pe  = (float*)(ws + 1720320);      // 768 KiB
    float* c1  = (float*)(ws + 2506752);      // 1 MiB
    float* c2  = (float*)(ws + 3555328);      // 1 MiB
    unsigned short* logits = (unsigned short*)(ws + 4603904);  // 48 MiB bf16

    prep_weights<<<288, 256, 0, stream>>>(mW1, mW2, W1T, W2T);
    prep_proj<<<2048, 256, 0, stream>>>(invs, equis, qW, qb, kW, kb,
                                        inv_inW, inv_inb, equi_inW, qm, km, hf, pe);
    prep_c12<<<2048, 256, 0, stream>>>(qm, km, mW1, mb1, c1, c2);
    semla_gemm<<<4096, 256, GA_BYTES, stream>>>(equis, edges, mb2, W1T, W2T,
                                                c1, c2, (float*)d_out, logits);
    semla_attn<<<1024, 256, BA_BYTES, stream>>>(adj, logits, hf, pe,
                                                inv_outW, inv_outb, equi_outW,
                                                (float*)d_out);
}

// Round 3
// 168.037 us; speedup vs baseline: 3.6665x; 1.6432x over previous
//
#include <hip/hip_runtime.h>
#include <hip/hip_bf16.h>
#include <math.h>

// ---------------------------------------------------------------------------
// SemlaSelfAttention — MI355X (gfx950)
//   prep_weights : bf16-transpose W1(K=128 tail), W2
//   prep_proj    : qm, km, hf, pe projections (f32)
//   prep_c12     : rank-folded qm/km contributions to GEMM1 bias
//   prep_T       : hfT/peT/WoT/EoT bf16 transposes (LDS-tiled)
//   semla_gemm   : per (b,q,jc): feats -> GEMM1(K=128) -> silu -> GEMM2
//                  -> edge cols f32 to out, attn cols (bias+mask, bf16)
//                     TRANSPOSED to PT[bq][n][j]
//   semla_einsum : per (b,c,qc): reg-softmax over 64 P^T rows + w, MFMA
//                  against hfT/peT -> OIb/OEb (bf16)
//   semla_proj   : MFMA GEMMs OIb@WoT+b -> inv_updates, OEb@EoT -> equi_updates
// ---------------------------------------------------------------------------

typedef __attribute__((ext_vector_type(8))) short short8;
typedef __attribute__((ext_vector_type(8))) __bf16 bf16x8;
typedef __attribute__((ext_vector_type(4))) float f32x4;

constexpr int EQUI_OFF = 0;          // 4*256*3*64 floats
constexpr int INV_OFF  = 196608;     // 4*256*256
constexpr int EDGE_OFF = 458752;     // 4*256*256*64

__device__ __forceinline__ unsigned short f2bf(float x) {
    unsigned u = __builtin_bit_cast(unsigned, x);
    u = u + 0x7FFFu + ((u >> 16) & 1u);   // RNE
    return (unsigned short)(u >> 16);
}
__device__ __forceinline__ unsigned pack2(float a, float b) {
    return (unsigned)f2bf(a) | ((unsigned)f2bf(b) << 16);
}
__device__ __forceinline__ float bf2f(unsigned short u) {
    return __builtin_bit_cast(float, ((unsigned)u) << 16);
}
__device__ __forceinline__ f32x4 MFMA(short8 a, short8 b, f32x4 c) {
    return __builtin_amdgcn_mfma_f32_16x16x32_bf16(
        __builtin_bit_cast(bf16x8, a), __builtin_bit_cast(bf16x8, b), c, 0, 0, 0);
}

// ---------------------------------------------------------------------------
// prep kernels
// ---------------------------------------------------------------------------
__global__ void prep_weights(const float* __restrict__ mW1, const float* __restrict__ mW2,
                             short* __restrict__ W1T, short* __restrict__ W2T) {
    int idx = blockIdx.x * 256 + threadIdx.x;           // grid = 288*256
    if (idx < 32768) {                                  // W1T[n][kk] = mW1[128+kk][n]
        int n = idx >> 7, kk = idx & 127;
        W1T[idx] = (short)f2bf(mW1[(128 + kk) * 256 + n]);
    } else {                                            // W2T[n][f] = mW2[f][n]
        int i2 = idx - 32768;
        int n = i2 >> 8, f = i2 & 255;
        W2T[i2] = (short)f2bf(mW2[f * 160 + n]);
    }
}

__global__ void prep_proj(const float* __restrict__ invs, const float* __restrict__ equis,
                          const float* __restrict__ qW, const float* __restrict__ qb,
                          const float* __restrict__ kW, const float* __restrict__ kb,
                          const float* __restrict__ inv_inW, const float* __restrict__ inv_inb,
                          const float* __restrict__ equi_inW,
                          float* __restrict__ qm, float* __restrict__ km,
                          float* __restrict__ hf, float* __restrict__ pe) {
    int tid = threadIdx.x;
    if (blockIdx.x < 1024) {
        int r = blockIdx.x;
        __shared__ float sInv[256];
        sInv[tid] = invs[r * 256 + tid];
        __syncthreads();
        if (tid < 64) {
            float acc = qb[tid];
            for (int f = 0; f < 256; ++f) acc += sInv[f] * qW[f * 64 + tid];
            qm[r * 64 + tid] = acc;
        } else if (tid < 128) {
            int c = tid - 64;
            float acc = kb[c];
            for (int f = 0; f < 256; ++f) acc += sInv[f] * kW[f * 64 + c];
            km[r * 64 + c] = acc;
        }
        float acch = inv_inb[tid];
        for (int f = 0; f < 256; ++f) acch += sInv[f] * inv_inW[f * 256 + tid];
        hf[r * 256 + tid] = acch;
    } else {
        int rn = blockIdx.x - 1024;
        if (tid < 192) {
            int d = tid >> 6, c = tid & 63;
            const float* erow = equis + (size_t)rn * 192 + d * 64;
            float acc = 0.f;
            for (int f = 0; f < 64; ++f) acc += erow[f] * equi_inW[f * 64 + c];
            pe[rn * 192 + d * 64 + c] = acc;
        }
    }
}

__global__ void prep_c12(const float* __restrict__ qm, const float* __restrict__ km,
                         const float* __restrict__ mW1, const float* __restrict__ mb1,
                         float* __restrict__ c1, float* __restrict__ c2) {
    int tid = threadIdx.x;
    __shared__ float s[64];
    if (blockIdx.x < 1024) {
        int r = blockIdx.x;
        if (tid < 64) s[tid] = qm[r * 64 + tid];
        __syncthreads();
        float acc = mb1[tid];
        #pragma unroll 8
        for (int k = 0; k < 64; ++k) acc = fmaf(s[k], mW1[k * 256 + tid], acc);
        c1[r * 256 + tid] = acc;
    } else {
        int r = blockIdx.x - 1024;
        if (tid < 64) s[tid] = km[r * 64 + tid];
        __syncthreads();
        float acc = 0.f;
        #pragma unroll 8
        for (int k = 0; k < 64; ++k) acc = fmaf(s[k], mW1[(64 + k) * 256 + tid], acc);
        c2[r * 256 + tid] = acc;
    }
}

// LDS-tiled transposes -> bf16
__global__ void prep_T(const float* __restrict__ hf, const float* __restrict__ pe,
                       const float* __restrict__ inv_outW, const float* __restrict__ equi_outW,
                       unsigned short* __restrict__ hfT, unsigned short* __restrict__ peT,
                       unsigned short* __restrict__ WoT, unsigned short* __restrict__ EoT) {
    __shared__ float sT[64][65];
    int tid = threadIdx.x, bi = blockIdx.x;
    if (bi < 64) {            // hfT[b][hd][j] = hf[b,j,hd]
        int b = bi >> 4, t = bi & 15, tj = t >> 2, th = t & 3;
        #pragma unroll
        for (int i = 0; i < 16; ++i) { int idx = i * 256 + tid; int jl = idx >> 6, hl = idx & 63;
            sT[jl][hl] = hf[((size_t)(b * 256 + tj * 64 + jl)) * 256 + th * 64 + hl]; }
        __syncthreads();
        #pragma unroll
        for (int i = 0; i < 16; ++i) { int idx = i * 256 + tid; int hl = idx >> 6, jl = idx & 63;
            hfT[((size_t)(b * 256 + th * 64 + hl)) * 256 + tj * 64 + jl] = f2bf(sT[jl][hl]); }
    } else if (bi < 128) {    // peT[b][c][d][j] = pe[b,j,d,c]; d=3 row zeroed
        int i2 = bi - 64; int b = i2 >> 4, t = i2 & 15, tj = t >> 2, d = t & 3;
        if (d == 3) {
            #pragma unroll
            for (int i = 0; i < 16; ++i) { int idx = i * 256 + tid; int c = idx >> 6, jl = idx & 63;
                peT[((size_t)((b * 64 + c) * 4 + 3)) * 256 + tj * 64 + jl] = 0; }
        } else {
            #pragma unroll
            for (int i = 0; i < 16; ++i) { int idx = i * 256 + tid; int jl = idx >> 6, c = idx & 63;
                sT[jl][c] = pe[((size_t)(b * 256 + tj * 64 + jl)) * 192 + d * 64 + c]; }
            __syncthreads();
            #pragma unroll
            for (int i = 0; i < 16; ++i) { int idx = i * 256 + tid; int c = idx >> 6, jl = idx & 63;
                peT[((size_t)((b * 64 + c) * 4 + d)) * 256 + tj * 64 + jl] = f2bf(sT[jl][c]); }
        }
    } else if (bi < 144) {    // WoT[n][f] = inv_outW[f][n]
        int i2 = bi - 128; int tf = i2 >> 2, tn = i2 & 3;
        #pragma unroll
        for (int i = 0; i < 16; ++i) { int idx = i * 256 + tid; int fl = idx >> 6, nl = idx & 63;
            sT[fl][nl] = inv_outW[(size_t)(tf * 64 + fl) * 256 + tn * 64 + nl]; }
        __syncthreads();
        #pragma unroll
        for (int i = 0; i < 16; ++i) { int idx = i * 256 + tid; int nl = idx >> 6, fl = idx & 63;
            WoT[(size_t)(tn * 64 + nl) * 256 + tf * 64 + fl] = f2bf(sT[fl][nl]); }
    } else {                  // EoT[c'][c] = equi_outW[c][c']
        #pragma unroll
        for (int i = 0; i < 16; ++i) { int idx = i * 256 + tid; int cl = idx >> 6, c2 = idx & 63;
            sT[cl][c2] = equi_outW[cl * 64 + c2]; }
        __syncthreads();
        #pragma unroll
        for (int i = 0; i < 16; ++i) { int idx = i * 256 + tid; int c2 = idx >> 6, cl = idx & 63;
            EoT[c2 * 64 + cl] = f2bf(sT[cl][c2]); }
    }
}

// ---------------------------------------------------------------------------
// GEMM kernel: one block per (b,q,jc); 4 waves; ~34 KB LDS -> 4 blocks/CU
// ---------------------------------------------------------------------------
constexpr int GA_AH = 0;        // A: 64x128 bf16 / H: 64x256 bf16 / sPT: 96x68 bf16
constexpr int GA_EQ = 32768;    // 192 f32
constexpr int GA_MASK = 33536;  // 64 f32
constexpr int GA_BYTES = 33792;

__launch_bounds__(256, 4)
__global__ void semla_gemm(const float* __restrict__ equis, const float* __restrict__ edges,
                           const int* __restrict__ adj, const float* __restrict__ mb2,
                           const short* __restrict__ W1T, const short* __restrict__ W2T,
                           const float* __restrict__ c1, const float* __restrict__ c2,
                           float* __restrict__ out, unsigned short* __restrict__ PT) {
    extern __shared__ char smem[];
    float* sEQ   = (float*)(smem + GA_EQ);
    float* sMask = (float*)(smem + GA_MASK);

    const int tid  = threadIdx.x;
    const int lane = tid & 63;
    const int w    = tid >> 6;
    const int bid  = blockIdx.x;        // bq*4 + jc
    const int bq   = bid >> 2;
    const int jc   = bid & 3;
    const int b    = bq >> 8;

    const int lrow = lane & 15;
    const int kgrp = (lane >> 4) << 3;
    const int drow = (lane >> 4) << 2;

    if (tid < 192) sEQ[tid] = equis[(size_t)bq * 192 + tid];
    if (tid < 64)  sMask[tid] = adj[(size_t)bq * 256 + (jc << 6) + tid] ? 0.f : -1e30f;

    float c1v[4];
    #pragma unroll
    for (int ni = 0; ni < 4; ++ni)
        c1v[ni] = c1[bq * 256 + (w << 6) + (ni << 4) + lrow];
    const int ntiles = (w < 2) ? 3 : 2;
    const int nbase  = (w < 2) ? w * 48 : 96 + (w - 2) * 32;
    float b2v[3];
    #pragma unroll
    for (int ti = 0; ti < 3; ++ti)
        if (ti < ntiles) b2v[ti] = mb2[nbase + (ti << 4) + lrow];

    auto stA2 = [&](int row, int col, unsigned v) {     // A tile [64][128] bf16
        int byte = ((row << 8) + (col << 1)) ^ ((row & 7) << 4);
        *(unsigned*)(smem + GA_AH + byte) = v;
    };
    auto ldA = [&](int row, int kb) -> short8 {
        int byte = ((row << 8) + (kb << 1)) ^ ((row & 7) << 4);
        return *(const short8*)(smem + GA_AH + byte);
    };
    auto stH = [&](int row, int col, unsigned short v) { // H tile [64][256] bf16
        int byte = ((row << 9) + (col << 1)) ^ ((row & 7) << 4);
        *(unsigned short*)(smem + GA_AH + byte) = v;
    };
    auto ldH = [&](int row, int kb) -> short8 {
        int byte = ((row << 9) + (kb << 1)) ^ ((row & 7) << 4);
        return *(const short8*)(smem + GA_AH + byte);
    };

    __syncthreads();   // sEQ/sMask visible

    // ---- build A: cols 0..63 = dot(q,j), 64..127 = edges[b,q,j] ----
    {
        int r = tid >> 2, qq = tid & 3;
        const float* erow = equis + (size_t)((b << 8) + (jc << 6) + r) * 192;
        #pragma unroll
        for (int i = 0; i < 4; ++i) {
            int c4 = (i << 2) + qq;
            f32x4 a = (f32x4)(0.f);
            #pragma unroll
            for (int d = 0; d < 3; ++d) {
                f32x4 e  = *(const f32x4*)(erow + d * 64 + c4 * 4);
                f32x4 qv = *(const f32x4*)(sEQ + d * 64 + c4 * 4);
                a += e * qv;
            }
            stA2(r, c4 * 4,     pack2(a.x, a.y));
            stA2(r, c4 * 4 + 2, pack2(a.z, a.w));
        }
        const float* ebase = edges + ((size_t)bq * 256 + (jc << 6)) * 64;
        #pragma unroll
        for (int it = 0; it < 4; ++it) {
            int vi = it * 256 + tid;
            f32x4 v = ((const f32x4*)ebase)[vi];
            int rr = vi >> 4, c4 = vi & 15;
            stA2(rr, 64 + c4 * 4,     pack2(v.x, v.y));
            stA2(rr, 64 + c4 * 4 + 2, pack2(v.z, v.w));
        }
    }
    __syncthreads();

    // ---- GEMM1: H = silu(A @ W1[128:] + c1 + c2), K=128 ----
    f32x4 acc[4][4];
    #pragma unroll
    for (int mi = 0; mi < 4; ++mi)
        #pragma unroll
        for (int ni = 0; ni < 4; ++ni) acc[mi][ni] = (f32x4)(0.f);

    #pragma unroll
    for (int k0 = 0; k0 < 128; k0 += 32) {
        int kb = k0 + kgrp;
        short8 a0 = ldA(lrow, kb), a1 = ldA(16 + lrow, kb),
               a2 = ldA(32 + lrow, kb), a3 = ldA(48 + lrow, kb);
        short8 bf[4];
        #pragma unroll
        for (int ni = 0; ni < 4; ++ni)
            bf[ni] = *(const short8*)(W1T + ((w << 6) + (ni << 4) + lrow) * 128 + kb);
        #pragma unroll
        for (int ni = 0; ni < 4; ++ni) {
            acc[0][ni] = MFMA(a0, bf[ni], acc[0][ni]);
            acc[1][ni] = MFMA(a1, bf[ni], acc[1][ni]);
            acc[2][ni] = MFMA(a2, bf[ni], acc[2][ni]);
            acc[3][ni] = MFMA(a3, bf[ni], acc[3][ni]);
        }
    }
    __syncthreads();

    const float* c2base = c2 + ((size_t)((b << 8) + (jc << 6)) << 8);
    #pragma unroll
    for (int mi = 0; mi < 4; ++mi)
        #pragma unroll
        for (int r = 0; r < 4; ++r) {
            int row = (mi << 4) + drow + r;
            const float* c2row = c2base + (row << 8);
            #pragma unroll
            for (int ni = 0; ni < 4; ++ni) {
                int n = (w << 6) + (ni << 4) + lrow;
                float x = acc[mi][ni][r] + c1v[ni] + c2row[n];
                float h = x / (1.f + __expf(-x));
                stH(row, n, f2bf(h));
            }
        }
    __syncthreads();

    // ---- GEMM2: msgs = H @ W2 + b2 ----
    f32x4 acc2[4][3];
    #pragma unroll
    for (int mi = 0; mi < 4; ++mi)
        #pragma unroll
        for (int ti = 0; ti < 3; ++ti) acc2[mi][ti] = (f32x4)(0.f);

    #pragma unroll
    for (int k0 = 0; k0 < 256; k0 += 32) {
        int kb = k0 + kgrp;
        short8 a0 = ldH(lrow, kb), a1 = ldH(16 + lrow, kb),
               a2 = ldH(32 + lrow, kb), a3 = ldH(48 + lrow, kb);
        short8 bt[3];
        #pragma unroll
        for (int ti = 0; ti < 3; ++ti)
            if (ti < ntiles) bt[ti] = *(const short8*)(W2T + (nbase + (ti << 4) + lrow) * 256 + kb);
        #pragma unroll
        for (int ti = 0; ti < 3; ++ti)
            if (ti < ntiles) {
                acc2[0][ti] = MFMA(a0, bt[ti], acc2[0][ti]);
                acc2[1][ti] = MFMA(a1, bt[ti], acc2[1][ti]);
                acc2[2][ti] = MFMA(a2, bt[ti], acc2[2][ti]);
                acc2[3][ti] = MFMA(a3, bt[ti], acc2[3][ti]);
            }
    }
    __syncthreads();   // H fully consumed; smem[0..13KB) reused as sPT[96][68] bf16

    if (w < 2) {
        // attn cols: bias + mask -> bf16 -> transposed LDS tile
        #pragma unroll
        for (int mi = 0; mi < 4; ++mi)
            #pragma unroll
            for (int ti = 0; ti < 3; ++ti) {
                int n = nbase + (ti << 4) + lrow;
                #pragma unroll
                for (int r = 0; r < 4; ++r) {
                    int j = (mi << 4) + drow + r;
                    float v = acc2[mi][ti][r] + b2v[ti] + sMask[j];
                    *(unsigned short*)(smem + n * 136 + j * 2) = f2bf(v);
                }
            }
    } else {
        // edge cols: straight f32 to out
        #pragma unroll
        for (int mi = 0; mi < 4; ++mi)
            #pragma unroll
            for (int ti = 0; ti < 2; ++ti) {
                int n = nbase + (ti << 4) + lrow;
                #pragma unroll
                for (int r = 0; r < 4; ++r) {
                    int j = (jc << 6) + (mi << 4) + drow + r;
                    out[EDGE_OFF + ((size_t)bq * 256 + j) * 64 + (n - 96)] = acc2[mi][ti][r] + b2v[ti];
                }
            }
    }
    __syncthreads();

    // coalesced PT store: PT[bq*96+n][jc*64 .. +64]
    if (tid < 192) {
        int n = tid >> 1, half = tid & 1;
        const char* src = smem + n * 136 + half * 64;
        unsigned short* dst = PT + (((size_t)bq * 96 + n) << 8) + (jc << 6) + half * 32;
        #pragma unroll
        for (int i = 0; i < 4; ++i)
            *(short8*)(dst + i * 8) = *(const short8*)(src + i * 16);
    }
}

// ---------------------------------------------------------------------------
// einsum kernel: one block per (b, c, qc); softmax in regs + 1 MFMA chain
// ---------------------------------------------------------------------------
constexpr int ES_A = 0;        // 64x256 bf16 swizzled = 32768
constexpr int ES_W = 32768;    // 64 f32
constexpr int ES_BYTES = 33024;

__launch_bounds__(256, 4)
__global__ void semla_einsum(const unsigned short* __restrict__ PT,
                             const unsigned short* __restrict__ hfT,
                             const unsigned short* __restrict__ peT,
                             unsigned short* __restrict__ OIb, unsigned short* __restrict__ OEb) {
    extern __shared__ char smem[];
    float* sW = (float*)(smem + ES_W);
    const int tid = threadIdx.x, lane = tid & 63, w = tid >> 6;
    const int bi = blockIdx.x;
    const int qc = bi & 3;
    const int t  = bi >> 2;
    const int b  = t / 96;
    const int c  = t - 96 * b;
    const int lrow = lane & 15, kgrp = (lane >> 4) << 3, drow = (lane >> 4) << 2;

    // load 64 P^T rows (each contiguous 512B) into swizzled LDS
    #pragma unroll
    for (int i = 0; i < 8; ++i) {
        int id = i * 256 + tid; int row = id >> 5, ck = id & 31;
        size_t src = (((size_t)((b << 8) + (qc << 6) + row) * 96 + c) << 8) + ck * 16;
        short8 v = *(const short8*)(PT + src);
        int byte = ((row << 9) + (ck << 4)) ^ ((row & 7) << 4);
        *(short8*)(smem + ES_A + byte) = v;
    }
    __syncthreads();

    // softmax: row r = tid>>2, 4 threads/row x 64 elems, in registers
    {
        int r = tid >> 2, p = tid & 3;
        float v[64];
        #pragma unroll
        for (int i = 0; i < 8; ++i) {
            int ck = p * 8 + i;
            int byte = ((r << 9) + (ck << 4)) ^ ((r & 7) << 4);
            short8 x = *(const short8*)(smem + ES_A + byte);
            #pragma unroll
            for (int e = 0; e < 8; ++e) v[i * 8 + e] = bf2f((unsigned short)x[e]);
        }
        float m = v[0];
        #pragma unroll
        for (int i = 1; i < 64; ++i) m = fmaxf(m, v[i]);
        m = fmaxf(m, __shfl_xor(m, 1)); m = fmaxf(m, __shfl_xor(m, 2));
        float s = 0.f, q = 0.f;
        #pragma unroll
        for (int i = 0; i < 64; ++i) { float e = __expf(v[i] - m); v[i] = e; s += e; q = fmaf(e, e, q); }
        s += __shfl_xor(s, 1); s += __shfl_xor(s, 2);
        q += __shfl_xor(q, 1); q += __shfl_xor(q, 2);
        float rs = (s > 0.f) ? 1.f / s : 0.f;
        if (p == 0) sW[r] = sqrtf(q) * rs;
        #pragma unroll
        for (int i = 0; i < 8; ++i) {
            int ck = p * 8 + i;
            short8 o;
            #pragma unroll
            for (int e = 0; e < 8; ++e) o[e] = (short)f2bf(v[i * 8 + e] * rs);
            int byte = ((r << 9) + (ck << 4)) ^ ((r & 7) << 4);
            *(short8*)(smem + ES_A + byte) = o;
        }
    }
    __syncthreads();

    // MFMA: wave = M-tile; B from hfT (c<32) or peT (c>=32)
    const unsigned short* Bbase =
        (c < 32) ? hfT + (((size_t)((b << 8) + (c << 3) + (lrow & 7))) << 8)
                 : peT + (((size_t)((((b << 6) + (c - 32)) << 2) + (lrow & 3))) << 8);
    f32x4 acc = (f32x4)(0.f);
    #pragma unroll
    for (int k0 = 0; k0 < 256; k0 += 32) {
        int kb = k0 + kgrp;
        int byte = ((((w << 4) + lrow) << 9) + (kb << 1)) ^ ((lrow & 7) << 4);
        short8 a = *(const short8*)(smem + ES_A + byte);
        short8 bb = *(const short8*)(Bbase + kb);
        acc = MFMA(a, bb, acc);
    }
    const int nvalid = (c < 32) ? 8 : 3;
    if (lrow < nvalid) {
        #pragma unroll
        for (int r2 = 0; r2 < 4; ++r2) {
            int ql = (w << 4) + drow + r2;
            float val = acc[r2] * sW[ql];
            size_t grow = (size_t)((b << 8) + (qc << 6) + ql);
            if (c < 32) OIb[(grow << 8) + (c << 3) + lrow] = f2bf(val);
            else        OEb[(grow * 3 + lrow) * 64 + (c - 32)] = f2bf(val);
        }
    }
}

// ---------------------------------------------------------------------------
// final projections: MFMA GEMMs
//   bi<32 : inv_updates (1024x256) = OIb @ WoT^T... (A 64x256 tiles, N split 2)
//   bi>=32: equi_updates (3072x64) = OEb @ EoT
// ---------------------------------------------------------------------------
constexpr int PJ_BYTES = 32768;

__launch_bounds__(256, 4)
__global__ void semla_proj(const unsigned short* __restrict__ OIb,
                           const unsigned short* __restrict__ OEb,
                           const unsigned short* __restrict__ WoT,
                           const unsigned short* __restrict__ EoT,
                           const float* __restrict__ inv_outb, float* __restrict__ out) {
    extern __shared__ char smem[];
    const int tid = threadIdx.x, lane = tid & 63, w = tid >> 6;
    const int lrow = lane & 15, kgrp = (lane >> 4) << 3, drow = (lane >> 4) << 2;
    const int bi = blockIdx.x;

    if (bi < 32) {
        const int mb = bi >> 1, nb = bi & 1;
        #pragma unroll
        for (int i = 0; i < 8; ++i) {
            int id = i * 256 + tid; int row = id >> 5, ck = id & 31;
            short8 v = *(const short8*)(OIb + (((size_t)(mb * 64 + row)) << 8) + ck * 16);
            int byte = ((row << 9) + (ck << 4)) ^ ((row & 7) << 4);
            *(short8*)(smem + byte) = v;
        }
        __syncthreads();
        f32x4 acc[4][2];
        #pragma unroll
        for (int mi = 0; mi < 4; ++mi)
            #pragma unroll
            for (int ti = 0; ti < 2; ++ti) acc[mi][ti] = (f32x4)(0.f);
        #pragma unroll
        for (int k0 = 0; k0 < 256; k0 += 32) {
            int kb = k0 + kgrp;
            short8 a[4];
            #pragma unroll
            for (int mi = 0; mi < 4; ++mi) {
                int byte = ((((mi << 4) + lrow) << 9) + (kb << 1)) ^ ((lrow & 7) << 4);
                a[mi] = *(const short8*)(smem + byte);
            }
            #pragma unroll
            for (int ti = 0; ti < 2; ++ti) {
                int n = nb * 128 + w * 32 + (ti << 4) + lrow;
                short8 bb = *(const short8*)(WoT + n * 256 + kb);
                #pragma unroll
                for (int mi = 0; mi < 4; ++mi) acc[mi][ti] = MFMA(a[mi], bb, acc[mi][ti]);
            }
        }
        #pragma unroll
        for (int ti = 0; ti < 2; ++ti) {
            int n = nb * 128 + w * 32 + (ti << 4) + lrow;
            float bias = inv_outb[n];
            #pragma unroll
            for (int mi = 0; mi < 4; ++mi)
                #pragma unroll
                for (int r = 0; r < 4; ++r) {
                    int row = mb * 64 + (mi << 4) + drow + r;
                    out[INV_OFF + (size_t)row * 256 + n] = acc[mi][ti][r] + bias;
                }
        }
    } else {
        const int mb = bi - 32;     // 64 rows of OEb (3072x64)
        #pragma unroll
        for (int i = 0; i < 2; ++i) {
            int id = i * 256 + tid; int row = id >> 3, ck = id & 7;
            short8 v = *(const short8*)(OEb + (((size_t)(mb * 64 + row)) << 6) + ck * 16);
            int byte = ((row << 7) + (ck << 4)) ^ ((row & 7) << 4);
            *(short8*)(smem + byte) = v;
        }
        __syncthreads();
        f32x4 acc[4];
        #pragma unroll
        for (int ni = 0; ni < 4; ++ni) acc[ni] = (f32x4)(0.f);
        #pragma unroll
        for (int k0 = 0; k0 < 64; k0 += 32) {
            int kb = k0 + kgrp;
            int byte = ((((w << 4) + lrow) << 7) + (kb << 1)) ^ ((lrow & 7) << 4);
            short8 a = *(const short8*)(smem + byte);
            #pragma unroll
            for (int ni = 0; ni < 4; ++ni) {
                short8 bb = *(const short8*)(EoT + ((ni << 4) + lrow) * 64 + kb);
                acc[ni] = MFMA(a, bb, acc[ni]);
            }
        }
        #pragma unroll
        for (int ni = 0; ni < 4; ++ni)
            #pragma unroll
            for (int r = 0; r < 4; ++r) {
                int rowg = mb * 64 + (w << 4) + drow + r;
                int bq = rowg / 3, d = rowg - 3 * bq;
                out[EQUI_OFF + (size_t)bq * 192 + d * 64 + (ni << 4) + lrow] = acc[ni][r];
            }
    }
}

// ---------------------------------------------------------------------------
extern "C" void kernel_launch(void* const* d_in, const int* in_sizes, int n_in,
                              void* d_out, int out_size, void* d_ws, size_t ws_size,
                              hipStream_t stream) {
    const float* equis    = (const float*)d_in[0];
    const float* invs     = (const float*)d_in[1];
    const float* edges    = (const float*)d_in[2];
    const int*   adj      = (const int*)d_in[3];
    const float* qW       = (const float*)d_in[4];
    const float* qb       = (const float*)d_in[5];
    const float* kW       = (const float*)d_in[6];
    const float* kb       = (const float*)d_in[7];
    const float* mW1      = (const float*)d_in[8];
    const float* mb1      = (const float*)d_in[9];
    const float* mW2      = (const float*)d_in[10];
    const float* mb2      = (const float*)d_in[11];
    const float* inv_inW  = (const float*)d_in[12];
    const float* inv_inb  = (const float*)d_in[13];
    const float* inv_outW = (const float*)d_in[14];
    const float* inv_outb = (const float*)d_in[15];
    const float* equi_inW = (const float*)d_in[16];
    const float* equi_outW= (const float*)d_in[17];

    char* ws = (char*)d_ws;
    short* W1T = (short*)(ws + 0);                        //  64 KiB
    short* W2T = (short*)(ws + 65536);                    //  80 KiB
    float* qm  = (float*)(ws + 147456);                   // 256 KiB
    float* km  = (float*)(ws + 409600);                   // 256 KiB
    float* hf  = (float*)(ws + 671744);                   //   1 MiB
    float* pe  = (float*)(ws + 1720320);                  // 768 KiB
    float* c1  = (float*)(ws + 2506752);                  //   1 MiB
    float* c2  = (float*)(ws + 3555328);                  //   1 MiB
    unsigned short* PT  = (unsigned short*)(ws + 4603904);   // 48 MiB
    unsigned short* peT = (unsigned short*)(ws + 54935552);  // 512 KiB
    unsigned short* hfT = (unsigned short*)(ws + 147456);    // 512 KiB (over qm/km, dead after prep_c12)
    unsigned short* OIb = (unsigned short*)(ws + 55459840);  // 512 KiB
    unsigned short* OEb = (unsigned short*)(ws + 55984128);  // 384 KiB
    unsigned short* WoT = (unsigned short*)(ws + 56377344);  // 128 KiB
    unsigned short* EoT = (unsigned short*)(ws + 56508416);  //   8 KiB

    prep_weights<<<288, 256, 0, stream>>>(mW1, mW2, W1T, W2T);
    prep_proj<<<2048, 256, 0, stream>>>(invs, equis, qW, qb, kW, kb,
                                        inv_inW, inv_inb, equi_inW, qm, km, hf, pe);
    prep_c12<<<2048, 256, 0, stream>>>(qm, km, mW1, mb1, c1, c2);
    prep_T<<<145, 256, 0, stream>>>(hf, pe, inv_outW, equi_outW, hfT, peT, WoT, EoT);
    semla_gemm<<<4096, 256, GA_BYTES, stream>>>(equis, edges, adj, mb2, W1T, W2T,
                                                c1, c2, (float*)d_out, PT);
    semla_einsum<<<1536, 256, ES_BYTES, stream>>>(PT, hfT, peT, OIb, OEb);
    semla_proj<<<80, 256, PJ_BYTES, stream>>>(OIb, OEb, WoT, EoT, inv_outb, (float*)d_out);
}